// Round 15
// baseline (198.617 us; speedup 1.0000x reference)
//
#include <hip/hip_runtime.h>

// B=8, N=128, COOR=3, F=128, FILT=128
#define BB   8
#define NN   128
#define FF   128
#define KK   128

typedef float  f32x4  __attribute__((ext_vector_type(4)));
typedef short  bf16x8 __attribute__((ext_vector_type(8)));
typedef short  short4v __attribute__((ext_vector_type(4)));

__device__ __forceinline__ short f2bf(float x) {
    union { float f; unsigned u; } v; v.f = x;
    unsigned u = v.u + (0x7fffu + ((v.u >> 16) & 1u));   // RTNE
    return (short)(u >> 16);
}

// ===========================================================================
// DIAGNOSTIC 2 (sacrificial): R14's kernels, each repeated with laundered
// pointers so BOTH appear in rocprof top-5.
//   k_pre_mfma_diag: x24 -> P = dur/24
//   k_main_diag:     x8  -> M = dur/8 (same-address passes = replay steady
//                           state for HBM writeback)
//   Start/End timestamps of the two dispatches -> inter-kernel gap.
// Output remains bit-identical to R14 (every pass writes the same values).
// ===========================================================================

#define LROW 136   // 128 + 8 pad (shorts)

__global__ __launch_bounds__(256) void k_pre_mfma_diag(const float* __restrict__ vf_in,
                                                       const float* __restrict__ w_in,
                                                       const float* __restrict__ bias,
                                                       float* __restrict__ ac_in) {
    const int bx  = blockIdx.x;
    const int mt  = bx >> 2;
    const int ntq = bx & 3;
    const int tid = threadIdx.x;

    __shared__ short a_lds[16 * LROW];
    __shared__ short b_lds[64 * LROW];

    for (int o = 0; o < 24; ++o) {
        const float* vf = vf_in;
        const float* w  = w_in;
        float* ac = ac_in;
        asm volatile("" : "+v"(vf));
        asm volatile("" : "+v"(w));
        asm volatile("" : "+v"(ac));

        // ---- Stage A ----
        {
            const f32x4* vfp = (const f32x4*)vf + (size_t)mt * 512;
            const int m  = tid >> 4;
            const int k0 = (tid & 15) * 8;
#pragma unroll
            for (int q = 0; q < 2; ++q) {
                const f32x4 v = vfp[tid * 2 + q];
                short4v s;
                s.x = f2bf(v.x); s.y = f2bf(v.y); s.z = f2bf(v.z); s.w = f2bf(v.w);
                *(short4v*)(&a_lds[m * LROW + k0 + q * 4]) = s;
            }
        }
        // ---- Stage B ----
        {
            const int whalf = ntq >> 1;
            const int wcol0 = (ntq & 1) * 64;
            const int kloc  = tid >> 4;
            const int cq    = tid & 15;
#pragma unroll
            for (int kb = 0; kb < 8; ++kb) {
                const int k = kb * 16 + kloc;
                const f32x4 v = *(const f32x4*)(w + (size_t)(whalf * 128 + k) * KK
                                                  + wcol0 + cq * 4);
                b_lds[(cq * 4 + 0) * LROW + k] = f2bf(v.x);
                b_lds[(cq * 4 + 1) * LROW + k] = f2bf(v.y);
                b_lds[(cq * 4 + 2) * LROW + k] = f2bf(v.z);
                b_lds[(cq * 4 + 3) * LROW + k] = f2bf(v.w);
            }
        }
        __syncthreads();

        const int wid  = tid >> 6;
        const int lane = tid & 63;
        const int lg   = lane >> 4;
        const int ln   = lane & 15;
        const int nt   = ntq * 4 + wid;

        f32x4 acc = {0.f, 0.f, 0.f, 0.f};
#pragma unroll
        for (int s = 0; s < 4; ++s) {
            const int k0 = s * 32 + lg * 8;
            const bf16x8 af = *(const bf16x8*)(&a_lds[ln * LROW + k0]);
            const bf16x8 bf = *(const bf16x8*)(&b_lds[(wid * 16 + ln) * LROW + k0]);
            acc = __builtin_amdgcn_mfma_f32_16x16x32_bf16(af, bf, acc, 0, 0, 0);
        }

        const int ncol = nt * 16 + ln;
        const float hb = 0.5f * bias[ncol & 127];
#pragma unroll
        for (int r = 0; r < 4; ++r) {
            const int mrow = mt * 16 + lg * 4 + r;
            ac[(size_t)mrow * 256 + ncol] = acc[r] + hb;
        }
        __syncthreads();   // separate iterations (LDS reuse)
    }
}

__global__ __launch_bounds__(256) void k_main_diag(const float* __restrict__ dist,
                                                   const float* __restrict__ ac_in,
                                                   float* __restrict__ out_in) {
    const int bx  = blockIdx.x;
    const int b   = bx >> 8;
    const int rem = bx & 255;
    const int it  = rem >> 3;
    const int jt  = rem & 7;
    const int i0  = it * 4, j0 = jt * 16;
    const int tid = threadIdx.x;

    __shared__ float dl[192];
    if (tid < 192) {
        const int ti = tid / 48, r = tid % 48;
        dl[tid] = dist[((size_t)(b * NN + i0 + ti) * NN + j0) * 3 + r];
    }
    __syncthreads();

    const int k4 = tid & 31;
    const int rg = tid >> 5;
    const int ti = rg >> 1;
    const int jp = rg & 1;
    const int i  = i0 + ti;
    const float* dlt = dl + ti * 48;

    for (int o = 0; o < 8; ++o) {
        const float* ac = ac_in;
        float* out = out_in;
        asm volatile("" : "+v"(ac));
        asm volatile("" : "+v"(out));

        const float4* arow = (const float4*)(ac + (size_t)(b * NN + i) * 768) + k4;
        const float4 a0 = arow[0], a1 = arow[64], a2 = arow[128];
        float* obase = out + (size_t)(b * NN + i) * NN * KK;

#pragma unroll
        for (int p = 0; p < 8; ++p) {
            const int jj = 2 * p + jp;
            const int j  = j0 + jj;
            const float d0 = dlt[jj * 3], d1 = dlt[jj * 3 + 1], d2 = dlt[jj * 3 + 2];

            const float4* crow = (const float4*)(ac + (size_t)(b * NN + j) * 768)
                                 + 32 + k4;
            const float4 c0 = crow[0], c1 = crow[64], c2 = crow[128];

            f32x4 r;
            r.x = fmaf(d0, a0.x + c0.x, fmaf(d1, a1.x + c1.x, d2 * (a2.x + c2.x)));
            r.y = fmaf(d0, a0.y + c0.y, fmaf(d1, a1.y + c1.y, d2 * (a2.y + c2.y)));
            r.z = fmaf(d0, a0.z + c0.z, fmaf(d1, a1.z + c1.z, d2 * (a2.z + c2.z)));
            r.w = fmaf(d0, a0.w + c0.w, fmaf(d1, a1.w + c1.w, d2 * (a2.w + c2.w)));

            __builtin_nontemporal_store(r, (f32x4*)(obase + (size_t)j * KK + k4 * 4));
        }
    }
}

// ---------------------------------------------------------------------------
// Fallback (only if ws_size < 3 MB): fused, recomputes C per j. Slow but correct.
// ---------------------------------------------------------------------------
__global__ __launch_bounds__(256) void k_fused_slow(const float* __restrict__ vf,
                                                    const float* __restrict__ dist,
                                                    const float* __restrict__ w,
                                                    const float* __restrict__ bias,
                                                    float* __restrict__ out) {
    const int bi  = blockIdx.x;
    const int b   = bi >> 7;
    const int tid = threadIdx.x;
    __shared__ float arow[384];
    __shared__ float crow[384];

    for (int idx = tid; idx < 384; idx += 256) {
        const int c = idx >> 7, k = idx & 127;
        const float* v = vf + (size_t)bi * 384 + c * 128;
        float s = 0.f;
        for (int f = 0; f < 128; ++f) s = fmaf(v[f], w[f * 128 + k], s);
        arow[idx] = s;
    }
    __syncthreads();

    for (int j = 0; j < NN; ++j) {
        for (int idx = tid; idx < 384; idx += 256) {
            const int c = idx >> 7, k = idx & 127;
            const float* v = vf + (size_t)(b * NN + j) * 384 + c * 128;
            float s = 0.f;
            for (int f = 0; f < 128; ++f) s = fmaf(v[f], w[(128 + f) * 128 + k], s);
            crow[idx] = s;
        }
        __syncthreads();
        if (tid < 128) {
            const float* dj = dist + ((size_t)bi * NN + j) * 3;
            const float d0 = dj[0], d1 = dj[1], d2 = dj[2];
            const float sd = d0 + d1 + d2;
            const float r = fmaf(d0, arow[tid] + crow[tid],
                            fmaf(d1, arow[128 + tid] + crow[128 + tid],
                            fmaf(d2, arow[256 + tid] + crow[256 + tid], sd * bias[tid])));
            out[((size_t)bi * NN + j) * 128 + tid] = r;
        }
        __syncthreads();
    }
}

extern "C" void kernel_launch(void* const* d_in, const int* in_sizes, int n_in,
                              void* d_out, int out_size, void* d_ws, size_t ws_size,
                              hipStream_t stream) {
    const float* vf   = (const float*)d_in[0];   // [8,128,3,128]
    const float* dist = (const float*)d_in[1];   // [8,128,128,3]
    const float* w    = (const float*)d_in[2];   // [256,128]
    const float* bias = (const float*)d_in[3];   // [128]
    float* out = (float*)d_out;                  // [8,128,128,128]

    const size_t need = (size_t)BB * NN * 3 * 256 * sizeof(float);  // 3 MB
    if (ws_size >= need) {
        float* ac = (float*)d_ws;
        k_pre_mfma_diag<<<768, 256, 0, stream>>>(vf, w, bias, ac);
        k_main_diag<<<2048, 256, 0, stream>>>(dist, ac, out);
    } else {
        k_fused_slow<<<BB * NN, 256, 0, stream>>>(vf, dist, w, bias, out);
    }
}

// Round 16
// 43.811 us; speedup vs baseline: 4.5335x; 4.5335x over previous
//
#include <hip/hip_runtime.h>

// B=8, N=128, COOR=3, F=128, FILT=128
#define BB   8
#define NN   128
#define FF   128
#define KK   128

typedef float  f32x4  __attribute__((ext_vector_type(4)));
typedef short  bf16x8 __attribute__((ext_vector_type(8)));
typedef short  short4v __attribute__((ext_vector_type(4)));

__device__ __forceinline__ short f2bf(float x) {
    union { float f; unsigned u; } v; v.f = x;
    unsigned u = v.u + (0x7fffu + ((v.u >> 16) & 1u));   // RTNE
    return (short)(u >> 16);
}

// ---------------------------------------------------------------------------
// Kernel 1 (MFMA): AC[M=3072][256] = bf16(vf)[3072][128] @ bf16(wcat)[128][256]
// + 0.5*bias. R14 version byte-identical (measured P ~= 3.3us in R15 diag).
// ---------------------------------------------------------------------------
#define LROW 136   // 128 + 8 pad (shorts)

__global__ __launch_bounds__(256) void k_pre_mfma(const float* __restrict__ vf,
                                                  const float* __restrict__ w,
                                                  const float* __restrict__ bias,
                                                  float* __restrict__ ac) {
    const int bx  = blockIdx.x;
    const int mt  = bx >> 2;            // 0..191  M-tile
    const int ntq = bx & 3;             // 0..3    N-quad
    const int tid = threadIdx.x;

    __shared__ short a_lds[16 * LROW];
    __shared__ short b_lds[64 * LROW];

    // ---- Stage A: vf rows mt*16..+16 (fp32) -> bf16 a_lds[m][k] ----
    {
        const f32x4* vfp = (const f32x4*)vf + (size_t)mt * 512;
        const int m  = tid >> 4;
        const int k0 = (tid & 15) * 8;
#pragma unroll
        for (int q = 0; q < 2; ++q) {
            const f32x4 v = vfp[tid * 2 + q];
            short4v s;
            s.x = f2bf(v.x); s.y = f2bf(v.y); s.z = f2bf(v.z); s.w = f2bf(v.w);
            *(short4v*)(&a_lds[m * LROW + k0 + q * 4]) = s;
        }
    }
    // ---- Stage B: w[whalf*128 + k][wcol0 + nl] -> bf16 b_lds[nl][k] ----
    {
        const int whalf = ntq >> 1;
        const int wcol0 = (ntq & 1) * 64;
        const int kloc  = tid >> 4;
        const int cq    = tid & 15;
#pragma unroll
        for (int kb = 0; kb < 8; ++kb) {
            const int k = kb * 16 + kloc;
            const f32x4 v = *(const f32x4*)(w + (size_t)(whalf * 128 + k) * KK
                                              + wcol0 + cq * 4);
            b_lds[(cq * 4 + 0) * LROW + k] = f2bf(v.x);
            b_lds[(cq * 4 + 1) * LROW + k] = f2bf(v.y);
            b_lds[(cq * 4 + 2) * LROW + k] = f2bf(v.z);
            b_lds[(cq * 4 + 3) * LROW + k] = f2bf(v.w);
        }
    }
    __syncthreads();

    const int wid  = tid >> 6;
    const int lane = tid & 63;
    const int lg   = lane >> 4;
    const int ln   = lane & 15;
    const int nt   = ntq * 4 + wid;

    f32x4 acc = {0.f, 0.f, 0.f, 0.f};
#pragma unroll
    for (int s = 0; s < 4; ++s) {
        const int k0 = s * 32 + lg * 8;
        const bf16x8 af = *(const bf16x8*)(&a_lds[ln * LROW + k0]);
        const bf16x8 bf = *(const bf16x8*)(&b_lds[(wid * 16 + ln) * LROW + k0]);
        acc = __builtin_amdgcn_mfma_f32_16x16x32_bf16(af, bf, acc, 0, 0, 0);
    }

    const int ncol = nt * 16 + ln;
    const float hb = 0.5f * bias[ncol & 127];
#pragma unroll
    for (int r = 0; r < 4; ++r) {
        const int mrow = mt * 16 + lg * 4 + r;
        ac[(size_t)mrow * 256 + ncol] = acc[r] + hb;
    }
}

// ---------------------------------------------------------------------------
// Kernel 2: out[b,i,j,k] = sum_c d[b,i,j,c] * (A'[b,i,c,k] + C'[b,j,c,k])
// R14 structure; ONE change (cache-role inversion, from R15 diag):
//   - a/c reads: __builtin_nontemporal_load  -> bypass L2, live in 256MB LLC
//   - stores:    PLAIN float4                -> L2 write-combining at the
//                fill-kernel's 6.2 TB/s path (NT direct path measured 4.6)
// ---------------------------------------------------------------------------
__global__ __launch_bounds__(256) void k_main(const float* __restrict__ dist,
                                              const float* __restrict__ ac,
                                              float* __restrict__ out) {
    const int bx  = blockIdx.x;
    const int b   = bx >> 8;            // 256 blocks per batch
    const int rem = bx & 255;
    const int it  = rem >> 3;           // 0..31
    const int jt  = rem & 7;            // 0..7 (low bits -> XCD affinity on C)
    const int i0  = it * 4, j0 = jt * 16;
    const int tid = threadIdx.x;

    __shared__ float dl[192];           // [ti][jj][c] = 4 x 16 x 3
    if (tid < 192) {
        const int ti = tid / 48, r = tid % 48;
        dl[tid] = dist[((size_t)(b * NN + i0 + ti) * NN + j0) * 3 + r];
    }
    __syncthreads();

    const int k4 = tid & 31;
    const int rg = tid >> 5;            // 0..7
    const int ti = rg >> 1;             // 0..3, constant per WAVE
    const int jp = rg & 1;              // j parity within wave
    const int i  = i0 + ti;

    const f32x4* arow = (const f32x4*)(ac + (size_t)(b * NN + i) * 768) + k4;
    const f32x4 a0 = __builtin_nontemporal_load(arow);
    const f32x4 a1 = __builtin_nontemporal_load(arow + 64);
    const f32x4 a2 = __builtin_nontemporal_load(arow + 128);
    float* obase = out + (size_t)(b * NN + i) * NN * KK;
    const float* dlt = dl + ti * 48;

#pragma unroll
    for (int p = 0; p < 8; ++p) {
        const int jj = 2 * p + jp;
        const int j  = j0 + jj;
        const float d0 = dlt[jj * 3], d1 = dlt[jj * 3 + 1], d2 = dlt[jj * 3 + 2];

        const f32x4* crow = (const f32x4*)(ac + (size_t)(b * NN + j) * 768)
                            + 32 + k4;           // +128 floats: C-half
        const f32x4 c0 = __builtin_nontemporal_load(crow);
        const f32x4 c1 = __builtin_nontemporal_load(crow + 64);
        const f32x4 c2 = __builtin_nontemporal_load(crow + 128);

        f32x4 r;
        r.x = fmaf(d0, a0.x + c0.x, fmaf(d1, a1.x + c1.x, d2 * (a2.x + c2.x)));
        r.y = fmaf(d0, a0.y + c0.y, fmaf(d1, a1.y + c1.y, d2 * (a2.y + c2.y)));
        r.z = fmaf(d0, a0.z + c0.z, fmaf(d1, a1.z + c1.z, d2 * (a2.z + c2.z)));
        r.w = fmaf(d0, a0.w + c0.w, fmaf(d1, a1.w + c1.w, d2 * (a2.w + c2.w)));

        *(f32x4*)(obase + (size_t)j * KK + k4 * 4) = r;   // plain: L2 combines
    }
}

// ---------------------------------------------------------------------------
// Fallback (only if ws_size < 3 MB): fused, recomputes C per j. Slow but correct.
// ---------------------------------------------------------------------------
__global__ __launch_bounds__(256) void k_fused_slow(const float* __restrict__ vf,
                                                    const float* __restrict__ dist,
                                                    const float* __restrict__ w,
                                                    const float* __restrict__ bias,
                                                    float* __restrict__ out) {
    const int bi  = blockIdx.x;           // b*NN + i
    const int b   = bi >> 7;
    const int tid = threadIdx.x;
    __shared__ float arow[384];
    __shared__ float crow[384];

    for (int idx = tid; idx < 384; idx += 256) {
        const int c = idx >> 7, k = idx & 127;
        const float* v = vf + (size_t)bi * 384 + c * 128;
        float s = 0.f;
        for (int f = 0; f < 128; ++f) s = fmaf(v[f], w[f * 128 + k], s);
        arow[idx] = s;
    }
    __syncthreads();

    for (int j = 0; j < NN; ++j) {
        for (int idx = tid; idx < 384; idx += 256) {
            const int c = idx >> 7, k = idx & 127;
            const float* v = vf + (size_t)(b * NN + j) * 384 + c * 128;
            float s = 0.f;
            for (int f = 0; f < 128; ++f) s = fmaf(v[f], w[(128 + f) * 128 + k], s);
            crow[idx] = s;
        }
        __syncthreads();
        if (tid < 128) {
            const float* dj = dist + ((size_t)bi * NN + j) * 3;
            const float d0 = dj[0], d1 = dj[1], d2 = dj[2];
            const float sd = d0 + d1 + d2;
            const float r = fmaf(d0, arow[tid] + crow[tid],
                            fmaf(d1, arow[128 + tid] + crow[128 + tid],
                            fmaf(d2, arow[256 + tid] + crow[256 + tid], sd * bias[tid])));
            out[((size_t)bi * NN + j) * 128 + tid] = r;
        }
        __syncthreads();
    }
}

extern "C" void kernel_launch(void* const* d_in, const int* in_sizes, int n_in,
                              void* d_out, int out_size, void* d_ws, size_t ws_size,
                              hipStream_t stream) {
    const float* vf   = (const float*)d_in[0];   // [8,128,3,128]
    const float* dist = (const float*)d_in[1];   // [8,128,128,3]
    const float* w    = (const float*)d_in[2];   // [256,128]
    const float* bias = (const float*)d_in[3];   // [128]
    float* out = (float*)d_out;                  // [8,128,128,128]

    const size_t need = (size_t)BB * NN * 3 * 256 * sizeof(float);  // 3 MB
    if (ws_size >= need) {
        float* ac = (float*)d_ws;
        k_pre_mfma<<<768, 256, 0, stream>>>(vf, w, bias, ac);
        k_main<<<2048, 256, 0, stream>>>(dist, ac, out);
    } else {
        k_fused_slow<<<BB * NN, 256, 0, stream>>>(vf, dist, w, bias, out);
    }
}

// Round 17
// 27.269 us; speedup vs baseline: 7.2835x; 1.6066x over previous
//
#include <hip/hip_runtime.h>

// B=8, N=128, COOR=3, F=128, FILT=128
#define BB   8
#define NN   128
#define FF   128
#define KK   128

typedef float  f32x4  __attribute__((ext_vector_type(4)));
typedef short  bf16x8 __attribute__((ext_vector_type(8)));
typedef short  short4v __attribute__((ext_vector_type(4)));

__device__ __forceinline__ short f2bf(float x) {
    union { float f; unsigned u; } v; v.f = x;
    unsigned u = v.u + (0x7fffu + ((v.u >> 16) & 1u));   // RTNE
    return (short)(u >> 16);
}

// ---------------------------------------------------------------------------
// Kernel 1 (MFMA): AC[M=3072][256] = bf16(vf)[3072][128] @ bf16(wcat)[128][256]
// + 0.5*bias. R14 version byte-identical (measured P ~= 3.3us, R15 diag).
// ---------------------------------------------------------------------------
#define LROW 136   // 128 + 8 pad (shorts)

__global__ __launch_bounds__(256) void k_pre_mfma(const float* __restrict__ vf,
                                                  const float* __restrict__ w,
                                                  const float* __restrict__ bias,
                                                  float* __restrict__ ac) {
    const int bx  = blockIdx.x;
    const int mt  = bx >> 2;            // 0..191  M-tile
    const int ntq = bx & 3;             // 0..3    N-quad
    const int tid = threadIdx.x;

    __shared__ short a_lds[16 * LROW];
    __shared__ short b_lds[64 * LROW];

    // ---- Stage A: vf rows mt*16..+16 (fp32) -> bf16 a_lds[m][k] ----
    {
        const f32x4* vfp = (const f32x4*)vf + (size_t)mt * 512;
        const int m  = tid >> 4;
        const int k0 = (tid & 15) * 8;
#pragma unroll
        for (int q = 0; q < 2; ++q) {
            const f32x4 v = vfp[tid * 2 + q];
            short4v s;
            s.x = f2bf(v.x); s.y = f2bf(v.y); s.z = f2bf(v.z); s.w = f2bf(v.w);
            *(short4v*)(&a_lds[m * LROW + k0 + q * 4]) = s;
        }
    }
    // ---- Stage B: w[whalf*128 + k][wcol0 + nl] -> bf16 b_lds[nl][k] ----
    {
        const int whalf = ntq >> 1;
        const int wcol0 = (ntq & 1) * 64;
        const int kloc  = tid >> 4;
        const int cq    = tid & 15;
#pragma unroll
        for (int kb = 0; kb < 8; ++kb) {
            const int k = kb * 16 + kloc;
            const f32x4 v = *(const f32x4*)(w + (size_t)(whalf * 128 + k) * KK
                                              + wcol0 + cq * 4);
            b_lds[(cq * 4 + 0) * LROW + k] = f2bf(v.x);
            b_lds[(cq * 4 + 1) * LROW + k] = f2bf(v.y);
            b_lds[(cq * 4 + 2) * LROW + k] = f2bf(v.z);
            b_lds[(cq * 4 + 3) * LROW + k] = f2bf(v.w);
        }
    }
    __syncthreads();

    const int wid  = tid >> 6;
    const int lane = tid & 63;
    const int lg   = lane >> 4;
    const int ln   = lane & 15;
    const int nt   = ntq * 4 + wid;

    f32x4 acc = {0.f, 0.f, 0.f, 0.f};
#pragma unroll
    for (int s = 0; s < 4; ++s) {
        const int k0 = s * 32 + lg * 8;
        const bf16x8 af = *(const bf16x8*)(&a_lds[ln * LROW + k0]);
        const bf16x8 bf = *(const bf16x8*)(&b_lds[(wid * 16 + ln) * LROW + k0]);
        acc = __builtin_amdgcn_mfma_f32_16x16x32_bf16(af, bf, acc, 0, 0, 0);
    }

    const int ncol = nt * 16 + ln;
    const float hb = 0.5f * bias[ncol & 127];
#pragma unroll
    for (int r = 0; r < 4; ++r) {
        const int mrow = mt * 16 + lg * 4 + r;
        ac[(size_t)mrow * 256 + ncol] = acc[r] + hb;
    }
}

// ---------------------------------------------------------------------------
// Kernel 2: out[b,i,j,k] = sum_c d[b,i,j,c] * (A'[b,i,c,k] + C'[b,j,c,k])
// NEW layout vs R14 (single variable): one i-row per block. Grid 1024 = (b,i);
// block owns out[b,i,:,:] = 64 KB CONTIGUOUS; per iter the 8 waves write
// j = p*8+rg -> dense 4 KB front sweeping linearly (fill-kernel-like page
// locality for the NT stream). dist row = 384 consecutive floats, one
// coalesced stage. A-row loaded once per block (L1-shared across waves).
// NT stores + normal cached loads (best-known from R8/R16 A/Bs).
// ---------------------------------------------------------------------------
__global__ __launch_bounds__(256) void k_main(const float* __restrict__ dist,
                                              const float* __restrict__ ac,
                                              float* __restrict__ out) {
    const int bx  = blockIdx.x;         // 0..1023
    const int b   = bx >> 7;
    const int i   = bx & 127;
    const int tid = threadIdx.x;

    __shared__ float dl[384];           // dist[b,i,:,:] = [j][c]
    if (tid < 96) {
        ((f32x4*)dl)[tid] =
            ((const f32x4*)(dist + (size_t)(b * NN + i) * NN * 3))[tid];
    }
    __syncthreads();

    const int k4 = tid & 31;            // f32x4 index within 128 k's
    const int rg = tid >> 5;            // 0..7

    const f32x4* arow = (const f32x4*)(ac + (size_t)(b * NN + i) * 768) + k4;
    const f32x4 a0 = arow[0], a1 = arow[64], a2 = arow[128];
    float* obase = out + (size_t)(b * NN + i) * NN * KK;

#pragma unroll 4
    for (int p = 0; p < 16; ++p) {
        const int j = p * 8 + rg;
        const float d0 = dl[j * 3], d1 = dl[j * 3 + 1], d2 = dl[j * 3 + 2];

        const f32x4* crow = (const f32x4*)(ac + (size_t)(b * NN + j) * 768)
                            + 32 + k4;           // +128 floats: C-half
        const f32x4 c0 = crow[0], c1 = crow[64], c2 = crow[128];

        f32x4 r;
        r.x = fmaf(d0, a0.x + c0.x, fmaf(d1, a1.x + c1.x, d2 * (a2.x + c2.x)));
        r.y = fmaf(d0, a0.y + c0.y, fmaf(d1, a1.y + c1.y, d2 * (a2.y + c2.y)));
        r.z = fmaf(d0, a0.z + c0.z, fmaf(d1, a1.z + c1.z, d2 * (a2.z + c2.z)));
        r.w = fmaf(d0, a0.w + c0.w, fmaf(d1, a1.w + c1.w, d2 * (a2.w + c2.w)));

        __builtin_nontemporal_store(r, (f32x4*)(obase + (size_t)j * KK + k4 * 4));
    }
}

// ---------------------------------------------------------------------------
// Fallback (only if ws_size < 3 MB): fused, recomputes C per j. Slow but correct.
// ---------------------------------------------------------------------------
__global__ __launch_bounds__(256) void k_fused_slow(const float* __restrict__ vf,
                                                    const float* __restrict__ dist,
                                                    const float* __restrict__ w,
                                                    const float* __restrict__ bias,
                                                    float* __restrict__ out) {
    const int bi  = blockIdx.x;           // b*NN + i
    const int b   = bi >> 7;
    const int tid = threadIdx.x;
    __shared__ float arow[384];
    __shared__ float crow[384];

    for (int idx = tid; idx < 384; idx += 256) {
        const int c = idx >> 7, k = idx & 127;
        const float* v = vf + (size_t)bi * 384 + c * 128;
        float s = 0.f;
        for (int f = 0; f < 128; ++f) s = fmaf(v[f], w[f * 128 + k], s);
        arow[idx] = s;
    }
    __syncthreads();

    for (int j = 0; j < NN; ++j) {
        for (int idx = tid; idx < 384; idx += 256) {
            const int c = idx >> 7, k = idx & 127;
            const float* v = vf + (size_t)(b * NN + j) * 384 + c * 128;
            float s = 0.f;
            for (int f = 0; f < 128; ++f) s = fmaf(v[f], w[(128 + f) * 128 + k], s);
            crow[idx] = s;
        }
        __syncthreads();
        if (tid < 128) {
            const float* dj = dist + ((size_t)bi * NN + j) * 3;
            const float d0 = dj[0], d1 = dj[1], d2 = dj[2];
            const float sd = d0 + d1 + d2;
            const float r = fmaf(d0, arow[tid] + crow[tid],
                            fmaf(d1, arow[128 + tid] + crow[128 + tid],
                            fmaf(d2, arow[256 + tid] + crow[256 + tid], sd * bias[tid])));
            out[((size_t)bi * NN + j) * 128 + tid] = r;
        }
        __syncthreads();
    }
}

extern "C" void kernel_launch(void* const* d_in, const int* in_sizes, int n_in,
                              void* d_out, int out_size, void* d_ws, size_t ws_size,
                              hipStream_t stream) {
    const float* vf   = (const float*)d_in[0];   // [8,128,3,128]
    const float* dist = (const float*)d_in[1];   // [8,128,128,3]
    const float* w    = (const float*)d_in[2];   // [256,128]
    const float* bias = (const float*)d_in[3];   // [128]
    float* out = (float*)d_out;                  // [8,128,128,128]

    const size_t need = (size_t)BB * NN * 3 * 256 * sizeof(float);  // 3 MB
    if (ws_size >= need) {
        float* ac = (float*)d_ws;
        k_pre_mfma<<<768, 256, 0, stream>>>(vf, w, bias, ac);
        k_main<<<1024, 256, 0, stream>>>(dist, ac, out);
    } else {
        k_fused_slow<<<BB * NN, 256, 0, stream>>>(vf, dist, w, bias, out);
    }
}